// Round 2
// baseline (576.694 us; speedup 1.0000x reference)
//
#include <hip/hip_runtime.h>

#define BATCH 4
#define CIN 1024
#define T 512
#define HW 49
#define C 2048
#define D 128
#define L 101
#define HALF 50
#define OUTD 128

#define CH 32          // c-channels per chunk
#define NCHK 32        // chunks per block (K = 1024 per block = one input tensor)
#define PITCH 200      // LDS floats per c row (49 float4 + 1 pad float4)

// ---------------------------------------------------------------------------
// prep: transpose Wp [D][C] -> WpT [C][D], Wf [OUTD][L] -> WfT [L][OUTD]
// ---------------------------------------------------------------------------
__global__ __launch_bounds__(256) void prep_kernel(const float* __restrict__ Wp,
                                                   const float* __restrict__ Wf,
                                                   float* __restrict__ WpT,
                                                   float* __restrict__ WfT) {
    int tid = blockIdx.x * 256 + threadIdx.x;
    if (tid < C * D) {
        int c = tid >> 7, d = tid & 127;
        WpT[tid] = Wp[d * C + c];
    }
    if (tid < L * OUTD) {
        int l = tid >> 7, o = tid & 127;
        WfT[tid] = Wf[o * L + l];
    }
}

// ---------------------------------------------------------------------------
// fused: spatial-mean + projection (split-K over the two input tensors).
// grid = 4(b) * 128(t-tile of 4) * 2(kh: x1/x2) = 1024 blocks, 256 threads.
// Per chunk of 32 c: stage 32x196 floats (reg-prefetched), reduce to means
// mm[c][t], then acc[t][d-pair] += mm * WpT (4-way K-split across waves).
// Output: part[kh][b*T+t][d] fp32 partials (2 MB).
// ---------------------------------------------------------------------------
__global__ __launch_bounds__(256) void fused_kernel(const float* __restrict__ x1,
                                                    const float* __restrict__ x2,
                                                    const float* __restrict__ WpT,
                                                    float* __restrict__ part) {
    int bid = blockIdx.x;
    int kh = bid & 1;
    int tt = (bid >> 1) & 127;
    int b  = bid >> 8;
    int t0 = tt * 4;
    const float* src = kh ? x2 : x1;

    __shared__ __align__(16) float raw[CH * PITCH];   // 25.6 KB
    __shared__ __align__(16) float mm[CH * 4];        // means [c][t]
    __shared__ __align__(16) float2 red2[4 * 4 * 64]; // [ks][t][dl] 8 KB

    int tid = threadIdx.x;

    // --- precompute per-thread staging slots: s = tid + 256*i, s < 1568 ---
    // s -> c = s/49, k4 = s%49. Global float4 idx = base4 + c*6272 + k4.
    // base4 = ((b*1024*512) + t0)*49/4  (t0 % 4 == 0 -> exact)
    long long base4 = ((((long long)b << 19) + t0) * 49) >> 2;
    const float4* src4 = reinterpret_cast<const float4*>(src);
    const float4* gp[7];
    int lofs[7];
    bool act[7];
#pragma unroll
    for (int i = 0; i < 7; ++i) {
        int s = tid + 256 * i;
        act[i] = (s < 1568);
        int c = s / 49;
        int k4 = s - c * 49;
        if (!act[i]) { c = 0; k4 = 0; }
        gp[i] = src4 + base4 + (long long)c * 6272 + k4;
        lofs[i] = c * (PITCH / 4) + k4;
    }
    const long long CHUNK_STRIDE4 = (long long)CH * 6272;  // float4 per chunk

    float4 r[7];
    float2 acc[4];
#pragma unroll
    for (int t = 0; t < 4; ++t) acc[t] = make_float2(0.f, 0.f);

    int ks = tid >> 6;        // K-split within chunk (wave id)
    int dl = tid & 63;        // d-pair lane
    int rid = tid >> 1;       // mean-phase row id
    int mc = rid >> 2;        // c_local for mean
    int mt = rid & 3;         // t for mean
    int p  = tid & 1;

    const float2* WpT2 = reinterpret_cast<const float2*>(WpT);
    float4* raw4 = reinterpret_cast<float4*>(raw);

    // prologue: load chunk 0
#pragma unroll
    for (int i = 0; i < 7; ++i) if (act[i]) r[i] = gp[i][0];

    for (int ck = 0; ck < NCHK; ++ck) {
        __syncthreads();  // raw consumers (mean ck-1) and mm consumers (gemm ck-1) done
        // write staged regs to LDS
#pragma unroll
        for (int i = 0; i < 7; ++i) if (act[i]) raw4[lofs[i]] = r[i];
        // prefetch next chunk
        if (ck + 1 < NCHK) {
            long long off = (long long)(ck + 1) * CHUNK_STRIDE4;
#pragma unroll
            for (int i = 0; i < 7; ++i) if (act[i]) r[i] = gp[i][off];
        }
        __syncthreads();  // raw ready

        // mean: 128 rows (c,t), 2 threads/row, 24+24(+1) elements
        {
            const float* rowp = &raw[mc * PITCH + mt * 49];
            float s = 0.f;
#pragma unroll
            for (int j = 0; j < 24; ++j) s += rowp[p * 24 + j];
            if (p == 0) s += rowp[48];
            s += __shfl_xor(s, 1);
            if (p == 0) mm[mc * 4 + mt] = s * (1.0f / 49.0f);
        }
        __syncthreads();  // mm ready

        // gemm: 8 c-iters for this wave's K-split
        long long wrow0 = (long long)(kh * 1024 + ck * CH) * 64;
#pragma unroll
        for (int j = 0; j < 8; ++j) {
            int ci = ks * 8 + j;
            float4 m4 = *reinterpret_cast<const float4*>(&mm[ci * 4]);
            float2 w = WpT2[wrow0 + (long long)ci * 64 + dl];
            acc[0].x += m4.x * w.x; acc[0].y += m4.x * w.y;
            acc[1].x += m4.y * w.x; acc[1].y += m4.y * w.y;
            acc[2].x += m4.z * w.x; acc[2].y += m4.z * w.y;
            acc[3].x += m4.w * w.x; acc[3].y += m4.w * w.y;
        }
    }

    // epilogue: reduce 4 K-splits, write partials
    __syncthreads();
#pragma unroll
    for (int t = 0; t < 4; ++t) red2[(ks * 4 + t) * 64 + dl] = acc[t];
    __syncthreads();
    {
        int t = tid >> 6;  // reuse 256 threads: (t, dl)
        float2 v = red2[(0 + t) * 64 + dl];
        float2 v1 = red2[(4 + t) * 64 + dl];
        float2 v2 = red2[(8 + t) * 64 + dl];
        float2 v3 = red2[(12 + t) * 64 + dl];
        v.x += v1.x + v2.x + v3.x;
        v.y += v1.y + v2.y + v3.y;
        long long row = (long long)kh * (BATCH * T) + b * T + (t0 + t);
        reinterpret_cast<float2*>(part)[row * 64 + dl] = v;
    }
}

// ---------------------------------------------------------------------------
// norm: reduce 2 split-K partials + L2 normalize -> xn[b*T+t][d]
// ---------------------------------------------------------------------------
__global__ __launch_bounds__(128) void norm_kernel(const float* __restrict__ part,
                                                   float* __restrict__ xn) {
    int bt = blockIdx.x;
    int tid = threadIdx.x;
    float v = part[(long long)bt * D + tid] +
              part[(long long)(BATCH * T) * D + (long long)bt * D + tid];
    float sq = v * v;
#pragma unroll
    for (int off = 1; off < 64; off <<= 1) sq += __shfl_xor(sq, off);
    __shared__ float red[2];
    if ((tid & 63) == 0) red[tid >> 6] = sq;
    __syncthreads();
    float n2 = red[0] + red[1];
    float scale = 1.0f / fmaxf(sqrtf(n2), 1e-12f);
    xn[(long long)bt * D + tid] = v * scale;
}

// ---------------------------------------------------------------------------
// simfc: banded sims + FC + bias + relu (unchanged from verified round 1)
// ---------------------------------------------------------------------------
__global__ __launch_bounds__(128) void simfc_kernel(const float* __restrict__ xn,
                                                    const float* __restrict__ WfT,
                                                    const float* __restrict__ bf,
                                                    float* __restrict__ out) {
    int bt = blockIdx.x;
    int b = bt >> 9, t = bt & 511;
    int tid = threadIdx.x;
    __shared__ __align__(16) float q[D];
    __shared__ float sim[L];
    q[tid] = xn[bt * D + tid];
    __syncthreads();

    if (tid < L) {
        float acc = 0.f;
        int s = t + tid - HALF;
        if (s >= 0 && s < T) {
            const float4* xr = reinterpret_cast<const float4*>(xn + (((long long)b << 9) + s) * D);
            const float4* q4 = reinterpret_cast<const float4*>(q);
#pragma unroll
            for (int d4 = 0; d4 < D / 4; ++d4) {
                float4 xv = xr[d4];
                float4 qv = q4[d4];
                acc += qv.x * xv.x + qv.y * xv.y + qv.z * xv.z + qv.w * xv.w;
            }
        }
        sim[tid] = acc;
    }
    __syncthreads();

    float acc = bf[tid];
#pragma unroll 4
    for (int l = 0; l < L; ++l) acc += sim[l] * WfT[l * OUTD + tid];
    out[bt * OUTD + tid] = fmaxf(acc, 0.0f);
}

// ---------------------------------------------------------------------------
extern "C" void kernel_launch(void* const* d_in, const int* in_sizes, int n_in,
                              void* d_out, int out_size, void* d_ws, size_t ws_size,
                              hipStream_t stream) {
    const float* x1 = (const float*)d_in[0];
    const float* x2 = (const float*)d_in[1];
    const float* Wp = (const float*)d_in[2];
    const float* Wf = (const float*)d_in[3];
    const float* bf = (const float*)d_in[4];
    float* out = (float*)d_out;

    float* ws = (float*)d_ws;
    float* WpT  = ws;                  // 2048*128   = 262144 floats
    float* WfT  = WpT + 262144;        // 101*128    = 12928
    float* part = WfT + 12928;         // 2*4*512*128 = 524288
    float* xn   = part + 524288;       // 4*512*128  = 262144
    // total ~1.06M floats = 4.25 MB

    hipLaunchKernelGGL(prep_kernel, dim3(1024), dim3(256), 0, stream, Wp, Wf, WpT, WfT);
    hipLaunchKernelGGL(fused_kernel, dim3(1024), dim3(256), 0, stream, x1, x2, WpT, part);
    hipLaunchKernelGGL(norm_kernel, dim3(2048), dim3(128), 0, stream, part, xn);
    hipLaunchKernelGGL(simfc_kernel, dim3(2048), dim3(128), 0, stream, xn, WfT, bf, out);
}

// Round 3
// 224.536 us; speedup vs baseline: 2.5684x; 2.5684x over previous
//
#include <hip/hip_runtime.h>

#define BATCH 4
#define CIN 1024
#define T 512
#define HW 49
#define C 2048
#define D 128
#define L 101
#define HALF 50
#define OUTD 128

#if defined(__has_builtin)
#if __has_builtin(__builtin_amdgcn_global_load_lds)
#define HAS_GLLDS 1
#endif
#endif

__device__ __forceinline__ void gl2lds16(const float4* g, float4* l) {
#ifdef HAS_GLLDS
    __builtin_amdgcn_global_load_lds(
        (const __attribute__((address_space(1))) void*)g,
        (__attribute__((address_space(3))) void*)l, 16, 0, 0);
#else
    *l = *g;
#endif
}

// ---------------------------------------------------------------------------
// prep: tiled transpose Wp [D][C] -> WpT [C][D]; Wf [OUTD][L] -> WfT [L][OUTD]
// grid = 256 (Wp 32x32 tiles) + 51 (WfT scatter) = 307 blocks.
// ---------------------------------------------------------------------------
__global__ __launch_bounds__(256) void prep_kernel(const float* __restrict__ Wp,
                                                   const float* __restrict__ Wf,
                                                   float* __restrict__ WpT,
                                                   float* __restrict__ WfT) {
    __shared__ float tile[32][33];
    int bid = blockIdx.x;
    int tid = threadIdx.x;
    if (bid < 256) {
        int ct = bid & 63, dt = bid >> 6;      // 64 c-tiles, 4 d-tiles
        int c0 = ct * 32, d0 = dt * 32;
        int col = tid & 31, row = tid >> 5;    // 8 rows per pass
#pragma unroll
        for (int i = 0; i < 4; ++i) {
            int dl = row + i * 8;
            tile[dl][col] = Wp[(long long)(d0 + dl) * C + c0 + col];
        }
        __syncthreads();
#pragma unroll
        for (int i = 0; i < 4; ++i) {
            int cc = row + i * 8;
            WpT[(long long)(c0 + cc) * D + d0 + col] = tile[col][cc];
        }
    } else {
        int idx = (bid - 256) * 256 + tid;
        if (idx < L * OUTD) {
            int l = idx >> 7, o = idx & 127;
            WfT[idx] = Wf[o * L + l];
        }
    }
}

// ---------------------------------------------------------------------------
// mean: spatial mean over 49 -> feats[b][c][t].  128 rows/block, 32768 blocks.
// Staging via global_load_lds (linear lane order), 2 threads/row reduce.
// ---------------------------------------------------------------------------
__global__ __launch_bounds__(256) void mean_kernel(const float* __restrict__ x1,
                                                   const float* __restrict__ x2,
                                                   float* __restrict__ feats) {
    __shared__ __align__(16) float lds[128 * HW];        // 25088 B
    const long long Mrows = (long long)BATCH * CIN * T;  // 2097152 per input
    long long row0 = (long long)blockIdx.x * 128;
    const float* src;
    long long m0;
    int half;
    if (row0 < Mrows) { src = x1; m0 = row0; half = 0; }
    else              { src = x2; m0 = row0 - Mrows; half = 1; }

    const float4* src4 = reinterpret_cast<const float4*>(src) + (((long long)m0 * HW) >> 2);
    float4* lds4 = reinterpret_cast<float4*>(lds);
    int tid = threadIdx.x;
    // 128 rows * 49 floats = 1568 float4 = 6*256 + 32
#pragma unroll
    for (int i = 0; i < 6; ++i)
        gl2lds16(src4 + i * 256 + tid, lds4 + i * 256 + tid);
    if (tid < 32)
        gl2lds16(src4 + 1536 + tid, lds4 + 1536 + tid);
    __syncthreads();

    int r = tid >> 1, p = tid & 1;
    const float* rowp = &lds[r * HW + p * 24];
    float s0 = 0.f, s1 = 0.f, s2 = 0.f, s3 = 0.f;
#pragma unroll
    for (int j = 0; j < 6; ++j) {
        s0 += rowp[j];
        s1 += rowp[6 + j];
        s2 += rowp[12 + j];
        s3 += rowp[18 + j];
    }
    float s = (s0 + s1) + (s2 + s3);
    if (p == 0) s += lds[r * HW + 48];
    s += __shfl_xor(s, 1);
    if (p == 0) {
        long long m = m0 + r;
        long long b = m >> 19;                 // / (1024*512)
        long long rem = m & ((1LL << 19) - 1); // c*512 + t
        feats[(b << 20) + ((long long)half << 19) + rem] = s * (1.0f / 49.0f);
    }
}

// ---------------------------------------------------------------------------
// proj: x[b,t,d] = sum_c feats[b,c,t] * WpT[c,d], split-K.
// grid = 4(b) * 32(t-tile of 16) * 8(kc of 256 c) = 1024 blocks, 256 thr.
// ---------------------------------------------------------------------------
__global__ __launch_bounds__(256) void proj_kernel(const float* __restrict__ feats,
                                                   const float* __restrict__ WpT,
                                                   float* __restrict__ part) {
    int bid = blockIdx.x;
    int kc = bid & 7;
    int tt = (bid >> 3) & 31;
    int b  = bid >> 8;
    int c0 = kc * 256;
    int t0 = tt * 16;

    __shared__ __align__(16) float fl[256 * 16];   // 16 KB
    float4* fl4 = reinterpret_cast<float4*>(fl);
    const float4* feats4 = reinterpret_cast<const float4*>(feats);
    int tid = threadIdx.x;
#pragma unroll
    for (int i = 0; i < 4; ++i) {
        int s = i * 256 + tid;         // 1024 float4 total
        int c = s >> 2, tq = s & 3;
        gl2lds16(feats4 + (((long long)(b * C + c0 + c)) << 7) + (t0 >> 2) + tq,
                 fl4 + s);
    }
    __syncthreads();

    int dg = tid & 31;     // d = dg*4..+3
    int tg = tid >> 5;     // t = t0 + tg*2, +1
    float4 a0 = make_float4(0.f, 0.f, 0.f, 0.f);
    float4 a1 = make_float4(0.f, 0.f, 0.f, 0.f);
    const float4* WpT4 = reinterpret_cast<const float4*>(WpT);
#pragma unroll 8
    for (int c = 0; c < 256; ++c) {
        float2 m2 = *reinterpret_cast<const float2*>(&fl[c * 16 + tg * 2]);
        float4 wv = WpT4[(long long)(c0 + c) * 32 + dg];
        a0.x += m2.x * wv.x; a0.y += m2.x * wv.y; a0.z += m2.x * wv.z; a0.w += m2.x * wv.w;
        a1.x += m2.y * wv.x; a1.y += m2.y * wv.y; a1.z += m2.y * wv.z; a1.w += m2.y * wv.w;
    }

    float4* part4 = reinterpret_cast<float4*>(part);
    long long row = (long long)kc * (BATCH * T) + b * T + t0 + tg * 2;
    part4[row * 32 + dg] = a0;
    part4[(row + 1) * 32 + dg] = a1;
}

// ---------------------------------------------------------------------------
// norm: reduce 8 split-K partials + L2 normalize -> xn[b*T+t][d]
// ---------------------------------------------------------------------------
__global__ __launch_bounds__(128) void norm_kernel(const float* __restrict__ part,
                                                   float* __restrict__ xn) {
    int bt = blockIdx.x;
    int tid = threadIdx.x;
    float v = 0.f;
#pragma unroll
    for (int kc = 0; kc < 8; ++kc)
        v += part[((long long)kc * (BATCH * T) + bt) * D + tid];
    float sq = v * v;
#pragma unroll
    for (int off = 1; off < 64; off <<= 1) sq += __shfl_xor(sq, off);
    __shared__ float red[2];
    if ((tid & 63) == 0) red[tid >> 6] = sq;
    __syncthreads();
    float n2 = red[0] + red[1];
    float scale = 1.0f / fmaxf(sqrtf(n2), 1e-12f);
    xn[(long long)bt * D + tid] = v * scale;
}

// ---------------------------------------------------------------------------
// simfc: banded sims + FC + bias + relu (verified in rounds 1-2)
// ---------------------------------------------------------------------------
__global__ __launch_bounds__(128) void simfc_kernel(const float* __restrict__ xn,
                                                    const float* __restrict__ WfT,
                                                    const float* __restrict__ bf,
                                                    float* __restrict__ out) {
    int bt = blockIdx.x;
    int b = bt >> 9, t = bt & 511;
    int tid = threadIdx.x;
    __shared__ __align__(16) float q[D];
    __shared__ float sim[L];
    q[tid] = xn[(long long)bt * D + tid];
    __syncthreads();

    if (tid < L) {
        float acc = 0.f;
        int s = t + tid - HALF;
        if (s >= 0 && s < T) {
            const float4* xr = reinterpret_cast<const float4*>(xn + (((long long)b << 9) + s) * D);
            const float4* q4 = reinterpret_cast<const float4*>(q);
#pragma unroll
            for (int d4 = 0; d4 < D / 4; ++d4) {
                float4 xv = xr[d4];
                float4 qv = q4[d4];
                acc += qv.x * xv.x + qv.y * xv.y + qv.z * xv.z + qv.w * xv.w;
            }
        }
        sim[tid] = acc;
    }
    __syncthreads();

    float acc = bf[tid];
#pragma unroll 4
    for (int l = 0; l < L; ++l) acc += sim[l] * WfT[l * OUTD + tid];
    out[(long long)bt * OUTD + tid] = fmaxf(acc, 0.0f);
}

// ---------------------------------------------------------------------------
extern "C" void kernel_launch(void* const* d_in, const int* in_sizes, int n_in,
                              void* d_out, int out_size, void* d_ws, size_t ws_size,
                              hipStream_t stream) {
    const float* x1 = (const float*)d_in[0];
    const float* x2 = (const float*)d_in[1];
    const float* Wp = (const float*)d_in[2];
    const float* Wf = (const float*)d_in[3];
    const float* bf = (const float*)d_in[4];
    float* out = (float*)d_out;

    float* ws = (float*)d_ws;
    float* WpT   = ws;                   // 2048*128    = 262144 floats
    float* WfT   = WpT + 262144;         // 101*128     = 12928
    float* part  = WfT + 12928;          // 8*2048*128  = 2097152
    float* xn    = part + 2097152;       // 4*512*128   = 262144
    float* feats = xn + 262144;          // 4*2048*512  = 4194304
    // total ~6.83M floats = 27.3 MB

    hipLaunchKernelGGL(prep_kernel, dim3(307),   dim3(256), 0, stream, Wp, Wf, WpT, WfT);
    hipLaunchKernelGGL(mean_kernel, dim3(32768), dim3(256), 0, stream, x1, x2, feats);
    hipLaunchKernelGGL(proj_kernel, dim3(1024),  dim3(256), 0, stream, feats, WpT, part);
    hipLaunchKernelGGL(norm_kernel, dim3(2048),  dim3(128), 0, stream, part, xn);
    hipLaunchKernelGGL(simfc_kernel, dim3(2048), dim3(128), 0, stream, xn, WfT, bf, out);
}